// Round 1
// baseline (9675.560 us; speedup 1.0000x reference)
//
#include <hip/hip_runtime.h>
#include <hip/hip_bf16.h>
#include <cstddef>

// GPT-2 small forward: B=2, T=1024, L=6, H=12, C=768, V=50257
// All heavy GEMMs: bf16 MFMA (16x16x32), fp32 accumulate, fp32 in/out.

#define B_ 2
#define T_ 1024
#define BT 2048        // B_*T_
#define C_ 768
#define C3 2304        // 3*C
#define C4 3072        // 4*C
#define H_ 12
#define HD 64
#define L_ 6
#define V_ 50257

typedef short bf16x8 __attribute__((ext_vector_type(8)));
typedef float f32x4 __attribute__((ext_vector_type(4)));

static __device__ __forceinline__ short f2bf(float f) {
    unsigned u = __float_as_uint(f);
    unsigned r = (u + 0x7fffu + ((u >> 16) & 1u)) >> 16;
    return (short)r;
}

// ---------------------------------------------------------------- embed ----
__global__ __launch_bounds__(256) void embed_k(const int* __restrict__ idx,
                                               const float* __restrict__ emb,
                                               const float* __restrict__ pos,
                                               float* __restrict__ x) {
    int i = blockIdx.x * 256 + threadIdx.x;       // exact grid: BT*C_/256
    int bt = i / C_;
    int c = i - bt * C_;
    int t = bt & (T_ - 1);
    x[i] = emb[(size_t)idx[bt] * C_ + c] + pos[(size_t)t * C_ + c];
}

// ------------------------------------------------------------- layernorm ---
__global__ __launch_bounds__(256) void ln_k(const float* __restrict__ x,
                                            const float* __restrict__ w,
                                            const float* __restrict__ b,
                                            float* __restrict__ y) {
    int row = blockIdx.x;
    int tid = threadIdx.x;
    int lane = tid & 63, wv = tid >> 6;
    const float* xr = x + (size_t)row * C_;
    float v0 = xr[tid], v1 = xr[tid + 256], v2 = xr[tid + 512];
    float s = v0 + v1 + v2;
    #pragma unroll
    for (int off = 32; off; off >>= 1) s += __shfl_xor(s, off);
    __shared__ float wr[4];
    __shared__ float wr2[4];
    if (lane == 0) wr[wv] = s;
    __syncthreads();
    float mean = (wr[0] + wr[1] + wr[2] + wr[3]) * (1.0f / 768.0f);
    float d0 = v0 - mean, d1 = v1 - mean, d2 = v2 - mean;
    float sq = d0 * d0 + d1 * d1 + d2 * d2;
    #pragma unroll
    for (int off = 32; off; off >>= 1) sq += __shfl_xor(sq, off);
    if (lane == 0) wr2[wv] = sq;
    __syncthreads();
    float var = (wr2[0] + wr2[1] + wr2[2] + wr2[3]) * (1.0f / 768.0f);
    float rstd = rsqrtf(var + 1e-5f);
    float* yr = y + (size_t)row * C_;
    yr[tid]       = d0 * rstd * w[tid]       + b[tid];
    yr[tid + 256] = d1 * rstd * w[tid + 256] + b[tid + 256];
    yr[tid + 512] = d2 * rstd * w[tid + 512] + b[tid + 512];
}

// ------------------------------------------------------------------ gemm ---
// C[M,N] = A[M,K] @ B, fp32 in/out, bf16 MFMA compute.
// BTRANS=false: Bm is [K,N] row-major. BTRANS=true: Bm is [N,K] row-major.
// EPI: 0 = none; 1 = +bias, exact GELU; 2 = +resid; 3 = +bias +resid.
#define TM 128
#define TN 128
#define BK 32
#define LDT 40   // padded LDS row (bf16 elems): 80B rows keep b128 16B-aligned

template <int EPI, bool BTRANS>
__global__ __launch_bounds__(256) void gemm_k(const float* __restrict__ A,
                                              const float* __restrict__ Bm,
                                              const float* __restrict__ bias,
                                              const float* __restrict__ resid,
                                              float* __restrict__ D,
                                              int M, int N, int K) {
    __shared__ short As[TM * LDT];
    __shared__ short Bs[TN * LDT];
    int tid = threadIdx.x;
    int lane = tid & 63;
    int wid = tid >> 6;
    int wm = wid >> 1, wn = wid & 1;
    int l15 = lane & 15;
    int quad = lane >> 4;
    int m0 = blockIdx.y * TM;
    int n0 = blockIdx.x * TN;

    f32x4 acc[4][4];
    #pragma unroll
    for (int i = 0; i < 4; i++)
        #pragma unroll
        for (int j = 0; j < 4; j++)
            acc[i][j] = (f32x4){0.f, 0.f, 0.f, 0.f};

    for (int k0 = 0; k0 < K; k0 += BK) {
        __syncthreads();
        // stage A tile: [128][32] bf16, rows contiguous
        #pragma unroll
        for (int i = 0; i < 4; i++) {
            int e4 = tid + i * 256;            // 0..1023 float4 slots
            int m = e4 >> 3;                   // 8 float4 per 32-K row
            int kc = (e4 & 7) << 2;
            const float4 v = *(const float4*)(A + (size_t)(m0 + m) * K + k0 + kc);
            short* dst = &As[m * LDT + kc];
            dst[0] = f2bf(v.x); dst[1] = f2bf(v.y);
            dst[2] = f2bf(v.z); dst[3] = f2bf(v.w);
        }
        if (BTRANS) {
            // Bm [N][K]: rows of K contiguous -> direct [n][k] staging
            #pragma unroll
            for (int i = 0; i < 4; i++) {
                int e4 = tid + i * 256;
                int n = e4 >> 3;
                int kc = (e4 & 7) << 2;
                int gn = n0 + n;
                float4 v = make_float4(0.f, 0.f, 0.f, 0.f);
                if (gn < N) v = *(const float4*)(Bm + (size_t)gn * K + k0 + kc);
                short* dst = &Bs[n * LDT + kc];
                dst[0] = f2bf(v.x); dst[1] = f2bf(v.y);
                dst[2] = f2bf(v.z); dst[3] = f2bf(v.w);
            }
        } else {
            // Bm [K][N]: transpose into [n][k] during staging
            #pragma unroll
            for (int i = 0; i < 4; i++) {
                int e4 = tid + i * 256;
                int k = e4 >> 5;                 // 32 float4 per N-row of tile
                int nc = (e4 & 31) << 2;
                const float4 v = *(const float4*)(Bm + (size_t)(k0 + k) * N + n0 + nc);
                Bs[(nc + 0) * LDT + k] = f2bf(v.x);
                Bs[(nc + 1) * LDT + k] = f2bf(v.y);
                Bs[(nc + 2) * LDT + k] = f2bf(v.z);
                Bs[(nc + 3) * LDT + k] = f2bf(v.w);
            }
        }
        __syncthreads();
        bf16x8 af[4], bfr[4];
        #pragma unroll
        for (int t = 0; t < 4; t++) {
            af[t]  = *(const bf16x8*)&As[(wm * 64 + t * 16 + l15) * LDT + quad * 8];
            bfr[t] = *(const bf16x8*)&Bs[(wn * 64 + t * 16 + l15) * LDT + quad * 8];
        }
        #pragma unroll
        for (int mt = 0; mt < 4; mt++)
            #pragma unroll
            for (int nt = 0; nt < 4; nt++)
                acc[mt][nt] = __builtin_amdgcn_mfma_f32_16x16x32_bf16(
                    af[mt], bfr[nt], acc[mt][nt], 0, 0, 0);
    }

    #pragma unroll
    for (int mt = 0; mt < 4; mt++) {
        int row = m0 + wm * 64 + mt * 16 + quad * 4;
        #pragma unroll
        for (int nt = 0; nt < 4; nt++) {
            int col = n0 + wn * 64 + nt * 16 + l15;
            if (col < N) {
                #pragma unroll
                for (int r = 0; r < 4; r++) {
                    float v = acc[mt][nt][r];
                    int rr = row + r;
                    if (EPI == 1 || EPI == 3) v += bias[col];
                    if (EPI == 1) v = 0.5f * v * (1.0f + erff(v * 0.70710678118f));
                    if (EPI == 2 || EPI == 3) v += resid[(size_t)rr * N + col];
                    D[(size_t)rr * N + col] = v;
                }
            }
        }
    }
}

// ------------------------------------------------------------- attention ---
// One block per (q, b*H). qkv layout [B,T,3C]; q at hoff, k at C+hoff, v at 2C+hoff.
__global__ __launch_bounds__(256) void attn_k(const float* __restrict__ qkv,
                                              float* __restrict__ att_out) {
    int qidx = blockIdx.x;
    int bh = blockIdx.y;
    int b = bh / H_, h = bh - (bh / H_) * H_;
    int tid = threadIdx.x;
    int lane = tid & 63, w = tid >> 6;
    __shared__ float qs[HD];
    __shared__ float p[T_];
    __shared__ float wred[4];
    __shared__ float wred2[4];
    __shared__ float ored[256];

    const size_t base = (size_t)b * T_ * C3;
    int hoff = h * HD;
    if (tid < HD) qs[tid] = qkv[base + (size_t)qidx * C3 + hoff + tid];
    __syncthreads();

    int n = qidx + 1;
    // scores: wave w handles j = w, w+4, ...
    for (int j = w; j < n; j += 4) {
        float kv = qkv[base + (size_t)j * C3 + C_ + hoff + lane];
        float prod = qs[lane] * kv;
        #pragma unroll
        for (int off = 32; off; off >>= 1) prod += __shfl_xor(prod, off);
        if (lane == 0) p[j] = prod * 0.125f;   // 1/sqrt(64)
    }
    __syncthreads();

    // softmax
    float lmax = -1e30f;
    for (int j = tid; j < n; j += 256) lmax = fmaxf(lmax, p[j]);
    #pragma unroll
    for (int off = 32; off; off >>= 1) lmax = fmaxf(lmax, __shfl_xor(lmax, off));
    if (lane == 0) wred[w] = lmax;
    __syncthreads();
    float gmax = fmaxf(fmaxf(wred[0], wred[1]), fmaxf(wred[2], wred[3]));
    float lsum = 0.f;
    for (int j = tid; j < n; j += 256) {
        float e = expf(p[j] - gmax);
        p[j] = e;
        lsum += e;
    }
    #pragma unroll
    for (int off = 32; off; off >>= 1) lsum += __shfl_xor(lsum, off);
    if (lane == 0) wred2[w] = lsum;
    __syncthreads();
    float rinv = 1.0f / (wred2[0] + wred2[1] + wred2[2] + wred2[3]);

    // out[d] = sum_j p[j] * v[j][d]
    int d = tid & 63, grp = tid >> 6;
    float acc = 0.f;
    for (int j = grp; j < n; j += 4)
        acc += p[j] * qkv[base + (size_t)j * C3 + 2 * C_ + hoff + d];
    ored[tid] = acc;
    __syncthreads();
    if (tid < 64) {
        float s = ored[tid] + ored[tid + 64] + ored[tid + 128] + ored[tid + 192];
        att_out[((size_t)b * T_ + qidx) * C_ + hoff + tid] = s * rinv;
    }
}

// ---------------------------------------------------------------- launch ---
extern "C" void kernel_launch(void* const* d_in, const int* in_sizes, int n_in,
                              void* d_out, int out_size, void* d_ws, size_t ws_size,
                              hipStream_t stream) {
    const int*   idx   = (const int*)d_in[0];
    const float* emb   = (const float*)d_in[1];
    const float* pos   = (const float*)d_in[2];
    const float* Wqkv  = (const float*)d_in[3];
    const float* Wproj = (const float*)d_in[4];
    const float* ln1w  = (const float*)d_in[5];
    const float* ln1b  = (const float*)d_in[6];
    const float* ln2w  = (const float*)d_in[7];
    const float* ln2b  = (const float*)d_in[8];
    const float* W1    = (const float*)d_in[9];
    const float* b1    = (const float*)d_in[10];
    const float* W2    = (const float*)d_in[11];
    const float* b2    = (const float*)d_in[12];
    const float* lnfw  = (const float*)d_in[13];
    const float* lnfb  = (const float*)d_in[14];
    float* out = (float*)d_out;

    float* ws   = (float*)d_ws;
    float* x    = ws;                              // BT*C
    float* lnb  = x + (size_t)BT * C_;             // BT*C
    float* qkv  = lnb + (size_t)BT * C_;           // BT*3C
    float* att  = qkv + (size_t)BT * C3;           // BT*C
    float* hbuf = att + (size_t)BT * C_;           // BT*4C

    embed_k<<<(BT * C_) / 256, 256, 0, stream>>>(idx, emb, pos, x);

    for (int l = 0; l < L_; l++) {
        ln_k<<<BT, 256, 0, stream>>>(x, ln1w + (size_t)l * C_, ln1b + (size_t)l * C_, lnb);
        gemm_k<0, false><<<dim3(C3 / TN, BT / TM), 256, 0, stream>>>(
            lnb, Wqkv + (size_t)l * C_ * C3, nullptr, nullptr, qkv, BT, C3, C_);
        attn_k<<<dim3(T_, B_ * H_), 256, 0, stream>>>(qkv, att);
        gemm_k<2, false><<<dim3(C_ / TN, BT / TM), 256, 0, stream>>>(
            att, Wproj + (size_t)l * C_ * C_, nullptr, x, x, BT, C_, C_);
        ln_k<<<BT, 256, 0, stream>>>(x, ln2w + (size_t)l * C_, ln2b + (size_t)l * C_, lnb);
        gemm_k<1, false><<<dim3(C4 / TN, BT / TM), 256, 0, stream>>>(
            lnb, W1 + (size_t)l * C_ * C4, b1 + (size_t)l * C4, nullptr, hbuf, BT, C4, C_);
        gemm_k<3, false><<<dim3(C_ / TN, BT / TM), 256, 0, stream>>>(
            hbuf, W2 + (size_t)l * C4 * C_, b2 + (size_t)l * C_, x, x, BT, C_, C4);
    }

    ln_k<<<BT, 256, 0, stream>>>(x, lnfw, lnfb, lnb);
    // logits = lnb @ emb^T  (emb is [V, C] = B^T layout)
    gemm_k<0, true><<<dim3((V_ + TN - 1) / TN, BT / TM), 256, 0, stream>>>(
        lnb, emb, nullptr, nullptr, out, BT, V_, C_);
}